// Round 1
// baseline (21454.410 us; speedup 1.0000x reference)
//
#include <hip/hip_runtime.h>
#include <hip/hip_cooperative_groups.h>
#include <math.h>

namespace cg = cooperative_groups;

#define T_ 512
#define B_ 64
#define H_ 512
#define D_ 32
#define G7H (7*H_)      // 3584
#define JPB 2           // hidden channels per block
#define NBLK (H_/JPB)   // 256 blocks
#define NTHR 512        // 8 waves

// ---------------- P = embed @ W_x + b  (33 x 3584) ----------------
__global__ void precompute_P(const float* __restrict__ embed,
                             const float* __restrict__ Wg,
                             const float* __restrict__ bg,
                             float* __restrict__ P) {
    int idx = blockIdx.x * blockDim.x + threadIdx.x;
    if (idx >= 33 * G7H) return;
    int type = idx / G7H;
    int col  = idx % G7H;
    float acc = bg[col];
    #pragma unroll
    for (int d = 0; d < D_; ++d)
        acc += embed[type * D_ + d] * Wg[d * G7H + col];
    P[idx] = acc;
}

// ---------------- hT[j][b] = h0[b][j] ----------------
__global__ void init_hT(const float* __restrict__ h0, float* __restrict__ hbuf) {
    int idx = blockIdx.x * blockDim.x + threadIdx.x;
    if (idx >= B_ * H_) return;
    int b = idx / H_, j = idx % H_;
    hbuf[j * B_ + b] = h0[idx];
}

// ---------------- persistent recurrent kernel ----------------
__global__ void __launch_bounds__(NTHR, 2)
hawkes_main(const float* __restrict__ seq_dt, const int* __restrict__ seq_types,
            const float* __restrict__ Wg,   // (544, 3584)
            const float* __restrict__ c0, const float* __restrict__ ct0,
            const float* __restrict__ P,    // (33, 3584)
            float* __restrict__ hbuf,       // 2 x (H_*B_) transposed h buffers
            float* __restrict__ out) {
    __shared__ float Wl[14][H_];        // 28 KB: W_h[:, owned 14 cols], [c][k]
    __shared__ float part[14][8][B_];   // 28 KB: per-wave partial sums

    cg::grid_group grid = cg::this_grid();

    const int tid  = threadIdx.x;
    const int w    = tid >> 6;
    const int lane = tid & 63;
    const int j0   = blockIdx.x * JPB;

    // one-time: load W_h slice into LDS (k = tid covers 512 rows)
    #pragma unroll
    for (int c = 0; c < 14; ++c) {
        int gate = c >> 1, jl = c & 1;
        Wl[c][tid] = Wg[(size_t)(D_ + tid) * G7H + gate * H_ + j0 + jl];
    }

    // persistent cell state in registers (threads 0..127: (jl = tid>>6, b = tid&63))
    const int eb = tid & 63, ejl = tid >> 6;
    float c_s = 0.f, ct_s = 0.f;
    if (tid < 128) {
        c_s  = c0 [eb * H_ + j0 + ejl];
        ct_s = ct0[eb * H_ + j0 + ejl];
    }
    __syncthreads();

    const int kbase = w * 64;
    const size_t TBH = (size_t)T_ * B_ * H_;

    for (int t = 0; t < T_; ++t) {
        const float* rb = hbuf + (size_t)(t & 1) * (B_ * H_);
        float*       wb = hbuf + (size_t)((t + 1) & 1) * (B_ * H_);

        // phase A: wave w loads hT[kbase..kbase+63][lane] into registers
        float hreg[64];
        #pragma unroll
        for (int k = 0; k < 64; ++k)
            hreg[k] = rb[(kbase + k) * B_ + lane];

        // phase B: partial dot products for 14 columns over the k-slice
        float pc[14];
        #pragma unroll
        for (int c = 0; c < 14; ++c) pc[c] = 0.f;
        #pragma unroll
        for (int k4 = 0; k4 < 16; ++k4) {
            float4 wv[14];
            #pragma unroll
            for (int c = 0; c < 14; ++c)
                wv[c] = *(const float4*)&Wl[c][kbase + k4 * 4];
            #pragma unroll
            for (int q = 0; q < 4; ++q) {
                #pragma unroll
                for (int c = 0; c < 14; ++c)
                    pc[c] = fmaf(hreg[k4 * 4 + q], (&wv[c].x)[q], pc[c]);
            }
        }
        #pragma unroll
        for (int c = 0; c < 14; ++c) part[c][w][lane] = pc[c];
        __syncthreads();

        // phase C: reduce + gates + state update (threads 0..127)
        if (tid < 128) {
            const int b = eb, jl = ejl, j = j0 + jl;
            const int type = seq_types[t * B_ + b];
            const float dt = seq_dt[t * B_ + b];
            float g[7];
            #pragma unroll
            for (int gate = 0; gate < 7; ++gate) {
                float acc = P[(size_t)type * G7H + gate * H_ + j];
                #pragma unroll
                for (int ww = 0; ww < 8; ++ww) acc += part[gate * 2 + jl][ww][b];
                g[gate] = acc;
            }
            const float inpt   = 1.f / (1.f + __expf(-g[0]));
            const float forget = 1.f / (1.f + __expf(-g[1]));
            const float output = 1.f / (1.f + __expf(-g[2]));
            const float in_tar = 1.f / (1.f + __expf(-g[3]));
            const float fg_tar = 1.f / (1.f + __expf(-g[4]));
            const float z      = tanhf(g[5]);
            const float y      = 10.f * g[6];
            const float decay  = (fmaxf(y, 0.f) + log1pf(__expf(-fabsf(y)))) * 0.1f;

            const float c_i      = forget * c_s + inpt * z;
            const float ctar_new = fg_tar * ct_s + in_tar * z;
            const float c_t      = ctar_new + (c_i - ctar_new) * __expf(-decay * dt);
            const float h_t      = output * tanhf(c_t);
            c_s  = c_t;
            ct_s = ctar_new;

            const size_t base = (size_t)t * (B_ * H_) + (size_t)b * H_ + j;
            out[base]           = h_t;
            out[TBH + base]     = output;
            out[2 * TBH + base] = c_i;
            out[3 * TBH + base] = ctar_new;
            out[4 * TBH + base] = decay;
            wb[j * B_ + b] = h_t;
        }
        grid.sync();
    }
}

extern "C" void kernel_launch(void* const* d_in, const int* in_sizes, int n_in,
                              void* d_out, int out_size, void* d_ws, size_t ws_size,
                              hipStream_t stream) {
    const float* seq_dt    = (const float*)d_in[0];
    const int*   seq_types = (const int*)  d_in[1];
    const float* embed     = (const float*)d_in[2];
    const float* W_gates   = (const float*)d_in[3];
    const float* b_gates   = (const float*)d_in[4];
    const float* h0        = (const float*)d_in[5];
    const float* c0        = (const float*)d_in[6];
    const float* ct0       = (const float*)d_in[7];
    float* out = (float*)d_out;

    // workspace layout: P (33*3584 f32) | hT double buffer (2*H*B f32)
    float* P    = (float*)d_ws;
    float* hbuf = P + 33 * G7H;

    {
        int total = 33 * G7H;
        precompute_P<<<(total + 255) / 256, 256, 0, stream>>>(embed, W_gates, b_gates, P);
    }
    {
        int total = B_ * H_;
        init_hT<<<(total + 255) / 256, 256, 0, stream>>>(h0, hbuf);
    }
    {
        void* args[] = {(void*)&seq_dt, (void*)&seq_types, (void*)&W_gates,
                        (void*)&c0, (void*)&ct0, (void*)&P, (void*)&hbuf, (void*)&out};
        hipLaunchCooperativeKernel((void*)hawkes_main, dim3(NBLK), dim3(NTHR),
                                   args, 0, stream);
    }
}

// Round 2
// 4589.193 us; speedup vs baseline: 4.6750x; 4.6750x over previous
//
#include <hip/hip_runtime.h>
#include <math.h>

#define T_ 512
#define B_ 64
#define H_ 512
#define D_ 32
#define G7H (7*H_)      // 3584
#define JPB 2           // hidden channels per block
#define NBLK (H_/JPB)   // 256 blocks
#define NTHR 512        // 8 waves
#define GRPS 8
#define BLK_PER_GRP (NBLK/GRPS)   // 32

// ---------------- P = embed @ W_x + b  (33 x 3584) ----------------
__global__ void precompute_P(const float* __restrict__ embed,
                             const float* __restrict__ Wg,
                             const float* __restrict__ bg,
                             float* __restrict__ P) {
    int idx = blockIdx.x * blockDim.x + threadIdx.x;
    if (idx >= 33 * G7H) return;
    int type = idx / G7H;
    int col  = idx % G7H;
    float acc = bg[col];
    #pragma unroll
    for (int d = 0; d < D_; ++d)
        acc += embed[type * D_ + d] * Wg[d * G7H + col];
    P[idx] = acc;
}

// ---------------- hT[j][b] = h0[b][j] ----------------
__global__ void init_hT(const float* __restrict__ h0, float* __restrict__ hbuf) {
    int idx = blockIdx.x * blockDim.x + threadIdx.x;
    if (idx >= B_ * H_) return;
    int b = idx / H_, j = idx % H_;
    hbuf[j * B_ + b] = h0[idx];
}

// ---- two-level grid barrier, relaxed agent-scope atomics only (no L2 flush) ----
// sync layout (ints): c1[g][s] at g*16+s (64B apart), c2[s] at 128+s*16, gen at 192
__device__ __forceinline__ void grid_barrier(int* __restrict__ sync, int t, int grp) {
    __syncthreads();   // compiler emits s_waitcnt vmcnt(0) per wave -> sc1 stores drained
    if (threadIdx.x == 0) {
        const int s = t & 1;
        int* c1  = sync + grp * 16 + s;
        int* c2  = sync + 128 + s * 16;
        int* gen = sync + 192;
        int old = __hip_atomic_fetch_add(c1, 1, __ATOMIC_RELAXED, __HIP_MEMORY_SCOPE_AGENT);
        bool release = false;
        if (old == BLK_PER_GRP - 1) {
            __hip_atomic_store(c1, 0, __ATOMIC_RELAXED, __HIP_MEMORY_SCOPE_AGENT);
            int o2 = __hip_atomic_fetch_add(c2, 1, __ATOMIC_RELAXED, __HIP_MEMORY_SCOPE_AGENT);
            if (o2 == GRPS - 1) {
                __hip_atomic_store(c2, 0, __ATOMIC_RELAXED, __HIP_MEMORY_SCOPE_AGENT);
                asm volatile("s_waitcnt vmcnt(0)" ::: "memory");
                __hip_atomic_store(gen, t + 1, __ATOMIC_RELAXED, __HIP_MEMORY_SCOPE_AGENT);
                release = true;
            }
        }
        if (!release) {
            while (__hip_atomic_load(gen, __ATOMIC_RELAXED, __HIP_MEMORY_SCOPE_AGENT) < t + 1)
                __builtin_amdgcn_s_sleep(1);
        }
    }
    __syncthreads();
}

// ---------------- persistent recurrent kernel ----------------
__global__ void __launch_bounds__(NTHR, 2)
hawkes_main(const float* __restrict__ seq_dt, const int* __restrict__ seq_types,
            const float* __restrict__ Wg,   // (544, 3584)
            const float* __restrict__ c0, const float* __restrict__ ct0,
            const float* __restrict__ P,    // (33, 3584)
            float* __restrict__ hbuf,       // 2 x (H_*B_) transposed h buffers
            int*   __restrict__ sync,
            float* __restrict__ out) {
    __shared__ float Wl[14][H_];        // 28 KB
    __shared__ float part[14][8][B_];   // 28 KB

    const int tid  = threadIdx.x;
    const int w    = tid >> 6;
    const int lane = tid & 63;
    const int grp  = blockIdx.x & 7;          // heuristic XCD id
    const int j0   = grp * 64 + (blockIdx.x >> 3) * JPB;  // XCD-contiguous j range

    #pragma unroll
    for (int c = 0; c < 14; ++c) {
        int gate = c >> 1, jl = c & 1;
        Wl[c][tid] = Wg[(size_t)(D_ + tid) * G7H + gate * H_ + j0 + jl];
    }

    const int eb = tid & 63, ejl = tid >> 6;
    float c_s = 0.f, ct_s = 0.f;
    if (tid < 128) {
        c_s  = c0 [eb * H_ + j0 + ejl];
        ct_s = ct0[eb * H_ + j0 + ejl];
    }
    __syncthreads();

    const int kbase = w * 64;
    const size_t TBH = (size_t)T_ * B_ * H_;

    for (int t = 0; t < T_; ++t) {
        const float* rb = hbuf + (size_t)(t & 1) * (B_ * H_);
        float*       wb = hbuf + (size_t)((t + 1) & 1) * (B_ * H_);

        // phase A: wave w loads hT[kbase..kbase+63][lane] (agent-scope, L3-coherent)
        float hreg[64];
        #pragma unroll
        for (int k = 0; k < 64; ++k)
            hreg[k] = __hip_atomic_load(&rb[(kbase + k) * B_ + lane],
                                        __ATOMIC_RELAXED, __HIP_MEMORY_SCOPE_AGENT);

        // phase B: partial dot products for 14 columns over the k-slice
        float pc[14];
        #pragma unroll
        for (int c = 0; c < 14; ++c) pc[c] = 0.f;
        #pragma unroll
        for (int k4 = 0; k4 < 16; ++k4) {
            float4 wv[14];
            #pragma unroll
            for (int c = 0; c < 14; ++c)
                wv[c] = *(const float4*)&Wl[c][kbase + k4 * 4];
            #pragma unroll
            for (int q = 0; q < 4; ++q) {
                #pragma unroll
                for (int c = 0; c < 14; ++c)
                    pc[c] = fmaf(hreg[k4 * 4 + q], (&wv[c].x)[q], pc[c]);
            }
        }
        #pragma unroll
        for (int c = 0; c < 14; ++c) part[c][w][lane] = pc[c];
        __syncthreads();

        // phase C: reduce + gates + state update (threads 0..127)
        if (tid < 128) {
            const int b = eb, jl = ejl, j = j0 + jl;
            const int type = seq_types[t * B_ + b];
            const float dt = seq_dt[t * B_ + b];
            float g[7];
            #pragma unroll
            for (int gate = 0; gate < 7; ++gate) {
                float acc = P[(size_t)type * G7H + gate * H_ + j];
                #pragma unroll
                for (int ww = 0; ww < 8; ++ww) acc += part[gate * 2 + jl][ww][b];
                g[gate] = acc;
            }
            const float inpt   = 1.f / (1.f + __expf(-g[0]));
            const float forget = 1.f / (1.f + __expf(-g[1]));
            const float output = 1.f / (1.f + __expf(-g[2]));
            const float in_tar = 1.f / (1.f + __expf(-g[3]));
            const float fg_tar = 1.f / (1.f + __expf(-g[4]));
            const float z      = tanhf(g[5]);
            const float y      = 10.f * g[6];
            const float decay  = (fmaxf(y, 0.f) + log1pf(__expf(-fabsf(y)))) * 0.1f;

            const float c_i      = forget * c_s + inpt * z;
            const float ctar_new = fg_tar * ct_s + in_tar * z;
            const float c_t      = ctar_new + (c_i - ctar_new) * __expf(-decay * dt);
            const float h_t      = output * tanhf(c_t);
            c_s  = c_t;
            ct_s = ctar_new;

            const size_t base = (size_t)t * (B_ * H_) + (size_t)b * H_ + j;
            out[base]           = h_t;
            out[TBH + base]     = output;
            out[2 * TBH + base] = c_i;
            out[3 * TBH + base] = ctar_new;
            out[4 * TBH + base] = decay;
            __hip_atomic_store(&wb[j * B_ + b], h_t,
                               __ATOMIC_RELAXED, __HIP_MEMORY_SCOPE_AGENT);
        }
        grid_barrier(sync, t, grp);
    }
}

extern "C" void kernel_launch(void* const* d_in, const int* in_sizes, int n_in,
                              void* d_out, int out_size, void* d_ws, size_t ws_size,
                              hipStream_t stream) {
    const float* seq_dt    = (const float*)d_in[0];
    const int*   seq_types = (const int*)  d_in[1];
    const float* embed     = (const float*)d_in[2];
    const float* W_gates   = (const float*)d_in[3];
    const float* b_gates   = (const float*)d_in[4];
    const float* h0        = (const float*)d_in[5];
    const float* c0        = (const float*)d_in[6];
    const float* ct0       = (const float*)d_in[7];
    float* out = (float*)d_out;

    // workspace: P (33*3584) | hbuf (2*H*B) | sync (256 ints)
    float* P    = (float*)d_ws;
    float* hbuf = P + 33 * G7H;
    int*   sync = (int*)(hbuf + 2 * B_ * H_);

    hipMemsetAsync(sync, 0, 256 * sizeof(int), stream);
    {
        int total = 33 * G7H;
        precompute_P<<<(total + 255) / 256, 256, 0, stream>>>(embed, W_gates, b_gates, P);
    }
    {
        int total = B_ * H_;
        init_hT<<<(total + 255) / 256, 256, 0, stream>>>(h0, hbuf);
    }
    {
        void* args[] = {(void*)&seq_dt, (void*)&seq_types, (void*)&W_gates,
                        (void*)&c0, (void*)&ct0, (void*)&P, (void*)&hbuf,
                        (void*)&sync, (void*)&out};
        hipLaunchCooperativeKernel((void*)hawkes_main, dim3(NBLK), dim3(NTHR),
                                   args, 0, stream);
    }
}